// Round 20
// baseline (464.212 us; speedup 1.0000x reference)
//
#include <hip/hip_runtime.h>
#include <hip/hip_bf16.h>

#define BN_EPS 1e-5f
#define NB 64
#define NN 1000
#define NP 1024
#define HD 128
#define CS 8
#define NC 125  // NN/CS exactly
#define ZS 72   // z1b/z2b LDS row stride (shorts)

typedef short bf16x8 __attribute__((ext_vector_type(8)));
typedef float f32x4 __attribute__((ext_vector_type(4)));

__device__ __forceinline__ unsigned short f2b(float f) {
  __hip_bfloat16 h = __float2bfloat16(f);
  return *reinterpret_cast<unsigned short*>(&h);
}
__device__ __forceinline__ float b2f(unsigned short u) {
  unsigned v = ((unsigned)u) << 16;
  return __uint_as_float(v);
}
__device__ __forceinline__ unsigned tkey(float f) {
  unsigned u = __float_as_uint(f);
  return u ^ ((unsigned)((int)u >> 31) | 0x80000000u);
}
__device__ __forceinline__ float tdec(unsigned m) {
  unsigned u = (m & 0x80000000u) ? (m ^ 0x80000000u) : ~m;
  return __uint_as_float(u);
}

// ---------------------------------------------------------------------------
// Prep: WT (gat W transposed bf16), W1T, WoWgT = bf16(Wo@Wg0)^T, biash = bo@Wg0.
// ---------------------------------------------------------------------------
__global__ __launch_bounds__(256) void k_wprep(
    const float* __restrict__ Wg, const float* __restrict__ W1,
    const float* __restrict__ Wo, const float* __restrict__ bo,
    unsigned short* __restrict__ WT, unsigned short* __restrict__ W1T,
    unsigned short* __restrict__ WoWgT, float* __restrict__ biash) {
  int idx = blockIdx.x * 256 + threadIdx.x;
  if (idx < 49152) {
    int lay = idx >> 14, rem = idx & 16383;
    int n = rem >> 7, k = rem & 127;
    WT[idx] = f2b(Wg[lay * 16384 + k * 128 + n]);
  } else if (idx < 53248) {
    int j = idx - 49152;
    int n = j >> 6, k = j & 63;
    W1T[j] = f2b(W1[k * 64 + n]);
  } else if (idx < 61440) {
    int j = idx - 53248;
    int c = j >> 6, i = j & 63;
    float acc = 0.f;
#pragma unroll 4
    for (int d = 0; d < 128; ++d)
      acc = fmaf(Wo[i * 128 + d], Wg[d * 128 + c], acc);
    WoWgT[j] = f2b(acc);
  } else if (idx < 61568) {
    int c = idx - 61440;
    float acc = 0.f;
#pragma unroll 4
    for (int d = 0; d < 128; ++d) acc = fmaf(bo[d], Wg[d * 128 + c], acc);
    biash[c] = acc;
  }
}

// ---------------------------------------------------------------------------
// FUSED embed MLP + layer-0 GEMM, MFMA throughout (as round 17).
// ---------------------------------------------------------------------------
__global__ __launch_bounds__(256) void k_embed_gemm(
    const float* __restrict__ locs,
    const float* __restrict__ W0, const float* __restrict__ b0,
    const float* __restrict__ b1, const float* __restrict__ g1,
    const float* __restrict__ be1, const float* __restrict__ m1,
    const float* __restrict__ v1, const unsigned short* __restrict__ W1T,
    const unsigned short* __restrict__ WoWgT, const float* __restrict__ biash,
    const float* __restrict__ asrc, const float* __restrict__ adst,
    unsigned short* __restrict__ hb, float* __restrict__ es,
    float* __restrict__ ed) {
  __shared__ __align__(16) unsigned short z1b[64 * ZS];
  __shared__ __align__(16) unsigned short z2b[64 * ZS];
  int tid = threadIdx.x;
  long base = (long)blockIdx.x * 64;

  {
    int d = tid & 63;
    int q = tid >> 6;
    float w0x = W0[d], w0y = W0[64 + d], bb = b0[d];
#pragma unroll
    for (int g = 0; g < 4; ++g) {
#pragma unroll
      for (int i = 0; i < 4; ++i) {
        int n = g * 16 + q * 4 + i;
        float lx = locs[(base + n) * 2 + 0];
        float ly = locs[(base + n) * 2 + 1];
        z1b[n * ZS + d] = f2b(fmaxf(fmaf(lx, w0x, fmaf(ly, w0y, bb)), 0.f));
      }
    }
  }
  __syncthreads();

  int w = tid >> 6, l = tid & 63;
  int r = l & 15, g = l >> 4;

  {
    f32x4 acc[4];
#pragma unroll
    for (int n = 0; n < 4; ++n) acc[n] = {0.f, 0.f, 0.f, 0.f};
#pragma unroll
    for (int ks = 0; ks < 2; ++ks) {
      bf16x8 a = *(const bf16x8*)&z1b[(w * 16 + r) * ZS + ks * 32 + g * 8];
#pragma unroll
      for (int n = 0; n < 4; ++n) {
        bf16x8 bfr = *(const bf16x8*)&W1T[(n * 16 + r) * 64 + ks * 32 + g * 8];
        acc[n] = __builtin_amdgcn_mfma_f32_16x16x32_bf16(a, bfr, acc[n], 0, 0, 0);
      }
    }
#pragma unroll
    for (int n = 0; n < 4; ++n) {
      int col = n * 16 + r;
      float sc = g1[col] * rsqrtf(v1[col] + BN_EPS);
      float sh = be1[col] - m1[col] * sc;
      float bb = b1[col];
#pragma unroll
      for (int rr = 0; rr < 4; ++rr) {
        float v = fmaxf(fmaf(acc[n][rr] + bb, sc, sh), 0.f);
        z2b[(w * 16 + g * 4 + rr) * ZS + col] = f2b(v);
      }
    }
  }
  __syncthreads();

  {
    long rowbase = base + w * 16;
    f32x4 acc[8];
#pragma unroll
    for (int n = 0; n < 8; ++n) acc[n] = {0.f, 0.f, 0.f, 0.f};
#pragma unroll
    for (int ks = 0; ks < 2; ++ks) {
      bf16x8 a = *(const bf16x8*)&z2b[(w * 16 + r) * ZS + ks * 32 + g * 8];
#pragma unroll
      for (int n = 0; n < 8; ++n) {
        bf16x8 bfr = *(const bf16x8*)&WoWgT[(n * 16 + r) * 64 + ks * 32 + g * 8];
        acc[n] = __builtin_amdgcn_mfma_f32_16x16x32_bf16(a, bfr, acc[n], 0, 0, 0);
      }
    }
    float ps[4] = {0.f, 0.f, 0.f, 0.f};
    float pd[4] = {0.f, 0.f, 0.f, 0.f};
#pragma unroll
    for (int n = 0; n < 8; ++n) {
      int col = n * 16 + r;
      float bh = biash[col];
      float sa = asrc[col];
      float sd = adst[col];
#pragma unroll
      for (int rr = 0; rr < 4; ++rr) {
        float v = acc[n][rr] + bh;
        hb[(rowbase + g * 4 + rr) * 128 + col] = f2b(v);
        ps[rr] = fmaf(v, sa, ps[rr]);
        pd[rr] = fmaf(v, sd, pd[rr]);
      }
    }
#pragma unroll
    for (int rr = 0; rr < 4; ++rr) {
#pragma unroll
      for (int m = 1; m <= 8; m <<= 1) {
        ps[rr] += __shfl_xor(ps[rr], m, 64);
        pd[rr] += __shfl_xor(pd[rr], m, 64);
      }
    }
    if (r == 0) {
#pragma unroll
      for (int rr = 0; rr < 4; ++rr) {
        es[rowbase + g * 4 + rr] = ps[rr];
        ed[rowbase + g * 4 + rr] = pd[rr];
      }
    }
  }
}

// ---------------------------------------------------------------------------
// h = xb @ W via MFMA 16x16x32 bf16 (layers 1,2). No LDS.
// ---------------------------------------------------------------------------
__global__ __launch_bounds__(256) void k_gemm_e(
    const unsigned short* __restrict__ xb, const unsigned short* __restrict__ WT,
    const float* __restrict__ asrc, const float* __restrict__ adst,
    unsigned short* __restrict__ hb, float* __restrict__ es,
    float* __restrict__ ed) {
  int tid = threadIdx.x;
  int w = tid >> 6, l = tid & 63;
  long rowbase = (long)blockIdx.x * 64 + w * 16;
  int r = l & 15, g = l >> 4;

  f32x4 acc[8];
#pragma unroll
  for (int n = 0; n < 8; ++n) acc[n] = {0.f, 0.f, 0.f, 0.f};

#pragma unroll
  for (int ks = 0; ks < 4; ++ks) {
    bf16x8 a = *(const bf16x8*)&xb[(rowbase + r) * 128 + ks * 32 + g * 8];
#pragma unroll
    for (int n = 0; n < 8; ++n) {
      bf16x8 bfr = *(const bf16x8*)&WT[(n * 16 + r) * 128 + ks * 32 + g * 8];
      acc[n] = __builtin_amdgcn_mfma_f32_16x16x32_bf16(a, bfr, acc[n], 0, 0, 0);
    }
  }

  float ps[4] = {0.f, 0.f, 0.f, 0.f};
  float pd[4] = {0.f, 0.f, 0.f, 0.f};
#pragma unroll
  for (int n = 0; n < 8; ++n) {
    float sa = asrc[n * 16 + r];
    float sd = adst[n * 16 + r];
#pragma unroll
    for (int rr = 0; rr < 4; ++rr) {
      float v = acc[n][rr];
      hb[(rowbase + g * 4 + rr) * 128 + n * 16 + r] = f2b(v);
      ps[rr] = fmaf(v, sa, ps[rr]);
      pd[rr] = fmaf(v, sd, pd[rr]);
    }
  }
#pragma unroll
  for (int rr = 0; rr < 4; ++rr) {
#pragma unroll
    for (int m = 1; m <= 8; m <<= 1) {
      ps[rr] += __shfl_xor(ps[rr], m, 64);
      pd[rr] += __shfl_xor(pd[rr], m, 64);
    }
  }
  if (r == 0) {
#pragma unroll
    for (int rr = 0; rr < 4; ++rr) {
      es[rowbase + g * 4 + rr] = ps[rr];
      ed[rowbase + g * 4 + rr] = pd[rr];
    }
  }
}

#define CEX(a, b, up)                         \
  do {                                        \
    if (((a) > (b)) == (up)) {                \
      unsigned long long _t = (a);            \
      (a) = (b);                              \
      (b) = _t;                               \
    }                                         \
  } while (0)

// ---------------------------------------------------------------------------
// Fused sort + scan + coeffs + target-bucketing + chunk-sums + chunk-prefix.
// grid (NB, 4), 512 threads. dq==0 additionally: perm/e12/ab writes + CSR
// bucketing of targets by chunk c=k>>3 into tlist/boffs.
// ---------------------------------------------------------------------------
__global__ __launch_bounds__(512) void k_scpfx(
    const float* __restrict__ es, const float* __restrict__ ed,
    const unsigned short* __restrict__ hb, float2* __restrict__ e12,
    int* __restrict__ perm, float2* __restrict__ ab,
    int* __restrict__ tlist, int* __restrict__ boffs,
    float2* __restrict__ C12) {
  __shared__ unsigned long long keys[NP];      // 8192 B, live A..D
  __shared__ float smem[(NC + 1) * 64];        // 32256 B overlay: sc | s1,s2
  __shared__ float2 wtot[8];
  __shared__ int cnt[NC + 1];                  // bucket counters (dq==0)
  __shared__ int coffs[NC + 2];                // bucket starts
  float2* sc = (float2*)smem;
  float (*s1)[32] = (float(*)[32])smem;
  float (*s2)[32] = (float(*)[32])(smem + (NC + 1) * 32);
  int tid = threadIdx.x, b = blockIdx.x, dq = blockIdx.y;

  // ---- A: load + u64 bitonic sort ----
  for (int i = tid; i < NP; i += 512) {
    unsigned long long kk;
    if (i < NN) {
      kk = ((unsigned long long)tkey(es[b * NN + i]) << 32) | (unsigned)i;
    } else {
      kk = (0xFF800000ull << 32) | (unsigned)i;
    }
    keys[i] = kk;
  }
  __syncthreads();
  int i0 = tid * 2;
  {
    unsigned long long q0 = keys[i0], q1 = keys[i0 + 1];
    CEX(q0, q1, (i0 & 2) == 0);
    keys[i0] = q0; keys[i0 + 1] = q1;
  }
  __syncthreads();
  for (int k = 4; k <= NP; k <<= 1) {
    for (int j = k >> 1; j >= 2; j >>= 1) {
      int i = ((tid & ~(j - 1)) << 1) | (tid & (j - 1));
      int ixj = i | j;
      bool up = ((i & k) == 0);
      unsigned long long a = keys[i], c = keys[ixj];
      if ((a > c) == up) { keys[i] = c; keys[ixj] = a; }
      __syncthreads();
    }
    {
      unsigned long long q0 = keys[i0], q1 = keys[i0 + 1];
      CEX(q0, q1, (i0 & k) == 0);
      keys[i0] = q0; keys[i0 + 1] = q1;
    }
    __syncthreads();
  }

  // ---- B: decode + hierarchical scan of (e1,e2) -> sc; dq0 writes e12/perm ----
  float2 f0 = make_float2(0.f, 0.f), f1 = make_float2(0.f, 0.f);
  {
    unsigned long long k0 = keys[i0], k1 = keys[i0 + 1];
    if (i0 < NN) {
      float s = tdec((unsigned)(k0 >> 32));
      f0.x = __expf(s);
      f0.y = __expf(0.2f * s);
      if (dq == 0) {
        e12[b * NN + i0] = f0;
        perm[b * NN + i0] = (int)(unsigned)k0;
      }
    }
    if (i0 + 1 < NN) {
      float s = tdec((unsigned)(k1 >> 32));
      f1.x = __expf(s);
      f1.y = __expf(0.2f * s);
      if (dq == 0) {
        e12[b * NN + i0 + 1] = f1;
        perm[b * NN + i0 + 1] = (int)(unsigned)k1;
      }
    }
  }
  int lane = tid & 63, wid = tid >> 6;
  float tx = f0.x + f1.x, ty = f0.y + f1.y;
  float ix = tx, iy = ty;
#pragma unroll
  for (int dlt = 1; dlt < 64; dlt <<= 1) {
    float ox = __shfl_up(ix, dlt, 64);
    float oy = __shfl_up(iy, dlt, 64);
    if (lane >= dlt) { ix += ox; iy += oy; }
  }
  if (lane == 63) wtot[wid] = make_float2(ix, iy);
  __syncthreads();
  float bx = 0.f, by = 0.f;
#pragma unroll
  for (int ww = 0; ww < 8; ++ww) {
    if (ww < wid) {
      float2 t = wtot[ww];
      bx += t.x;
      by += t.y;
    }
  }
  float exx = bx + ix - tx, eyy = by + iy - ty;
  float in0x = exx + f0.x, in0y = eyy + f0.y;
  if (i0 < NN) sc[i0] = make_float2(in0x, in0y);
  if (i0 + 1 < NN) sc[i0 + 1] = make_float2(in0x + f1.x, in0y + f1.y);
  __syncthreads();

  // ---- C: coeffs + CSR bucketing (dq==0 only; block-uniform branch) ----
  if (dq == 0) {
    for (int c = tid; c <= NC; c += 512) cnt[c] = 0;
    __syncthreads();
    float s1tot = sc[NN - 1].x;
    int kreg[2] = {-1, -1};
#pragma unroll
    for (int rnd = 0; rnd < 2; ++rnd) {
      int i = tid + rnd * 512;
      if (i < NN) {
        float di = ed[b * NN + i];
        unsigned tt = tkey(-di);
        int lo = 0, hi = NP;
        while (lo < hi) {
          int mid = (lo + hi) >> 1;
          if ((unsigned)(keys[mid] >> 32) <= tt) lo = mid + 1; else hi = mid;
        }
        int k = lo;
        float p1 = (k > 0) ? sc[k - 1].x : 0.f;
        float p2 = (k > 0) ? sc[k - 1].y : 0.f;
        float Ed = __expf(di);
        float Ed2 = __expf(0.2f * di);
        float den = fmaf(Ed, s1tot - p1, Ed2 * p2);
        ab[b * NN + i] = make_float2(Ed / den, Ed2 / den);
        kreg[rnd] = k;
        atomicAdd(&cnt[k >> 3], 1);
      }
    }
    __syncthreads();
    if (tid == 0) {
      int s = 0;
      for (int c = 0; c <= NC; ++c) {
        coffs[c] = s;
        s += cnt[c];
      }
      coffs[NC + 1] = s;  // = NN
    }
    __syncthreads();
    for (int c = tid; c < NC + 2; c += 512) boffs[b * (NC + 2) + c] = coffs[c];
    for (int c = tid; c <= NC; c += 512) cnt[c] = coffs[c];  // running pos
    __syncthreads();
#pragma unroll
    for (int rnd = 0; rnd < 2; ++rnd) {
      int i = tid + rnd * 512;
      if (i < NN) {
        int k = kreg[rnd];
        int c = k >> 3;
        int slot = atomicAdd(&cnt[c], 1);
        tlist[b * NN + slot] = i | ((k - (c << 3)) << 16);
      }
    }
  }
  __syncthreads();  // sc dead after this; s1/s2 may overwrite

  // ---- D: chunk gather via LDS keys -> chunk sums ----
  int d = tid & 31;
  int cl = tid >> 5;
  int dglob = dq * 32 + d;
  for (int c = cl; c < NC; c += 16) {
    float v1 = 0.f, v2 = 0.f;
#pragma unroll
    for (int u = 0; u < CS; ++u) {
      int j = c * CS + u;
      unsigned long long kk = keys[j];
      int p = (int)(unsigned)kk;
      float s = tdec((unsigned)(kk >> 32));
      float e1 = __expf(s), e2 = __expf(0.2f * s);
      float hv = b2f(hb[((long)b * NN + p) * HD + dglob]);
      v1 = fmaf(e1, hv, v1);
      v2 = fmaf(e2, hv, v2);
    }
    s1[c][d] = v1;
    s2[c][d] = v2;
  }
  __syncthreads();

  // ---- E: serial exclusive chunk prefix (+ totals) ----
  if (tid < 32) {
    float r = 0.f;
    for (int c = 0; c < NC; ++c) {
      float v = s1[c][tid];
      s1[c][tid] = r;
      r += v;
    }
    s1[NC][tid] = r;
  } else if (tid < 64) {
    int dd = tid - 32;
    float r = 0.f;
    for (int c = 0; c < NC; ++c) {
      float v = s2[c][dd];
      s2[c][dd] = r;
      r += v;
    }
    s2[NC][dd] = r;
  }
  __syncthreads();

  // ---- F: coalesced interleaved C12 store ----
  long basec = (long)b * (NC + 1) * HD + dq * 32;
  for (int i = tid; i < (NC + 1) * 32; i += 512) {
    int c = i >> 5, dd = i & 31;
    C12[basec + (long)c * HD + dd] = make_float2(s1[c][dd], s2[c][dd]);
  }
}

// ---------------------------------------------------------------------------
// Bucketed output. grid (NB, NC+1): block (b,c) owns all targets whose chunk
// is c. Loads the <=8 residual rows ONCE (via perm from hb), builds prefix
// tables P1/P2 in LDS, loads C12[c]+totals once, then each target is 2 LDS
// reads + a coalesced row write.
// ---------------------------------------------------------------------------
template <bool APPLY_BN>
__global__ __launch_bounds__(128) void k_out(
    const unsigned short* __restrict__ hb, const float2* __restrict__ C12,
    const float2* __restrict__ e12, const int* __restrict__ perm,
    const int* __restrict__ tlist, const int* __restrict__ boffs,
    const float2* __restrict__ ab, const float* __restrict__ bias,
    const float* __restrict__ bng, const float* __restrict__ bnb,
    const float* __restrict__ bnm, const float* __restrict__ bnv,
    float* __restrict__ xo, unsigned short* __restrict__ xbo) {
  __shared__ float P1[8][128];
  __shared__ float P2[8][128];
  int d = threadIdx.x, b = blockIdx.x, c = blockIdx.y;  // c in [0, NC]
  int start = boffs[b * (NC + 2) + c];
  int end = boffs[b * (NC + 2) + c + 1];
  if (start == end) return;  // block-uniform

  float p1 = 0.f, p2 = 0.f;
#pragma unroll
  for (int r = 0; r < 8; ++r) {
    P1[r][d] = p1;
    P2[r][d] = p2;
    int j = c * CS + r;
    if (j < NN) {
      int p = perm[b * NN + j];
      float2 e = e12[b * NN + j];
      float hv = b2f(hb[((long)b * NN + p) * HD + d]);
      p1 = fmaf(e.x, hv, p1);
      p2 = fmaf(e.y, hv, p2);
    }
  }
  __syncthreads();

  float2 base12 = C12[((long)b * (NC + 1) + c) * HD + d];
  float T1 = C12[((long)b * (NC + 1) + NC) * HD + d].x;
  float bs = bias[d];
  float sc = 0.f, sh = 0.f;
  if (APPLY_BN) {
    float g = bng[d], bb = bnb[d], m = bnm[d], v = bnv[d];
    sc = g * rsqrtf(v + BN_EPS);
    sh = bb - m * sc;
  }
  for (int t = start; t < end; ++t) {
    int packed = tlist[b * NN + t];
    int i = packed & 0xFFFF;
    int rel = packed >> 16;  // 0..7
    float2 coeff = ab[b * NN + i];
    float val = fmaf(coeff.x, T1 - base12.x - P1[rel][d],
                     fmaf(coeff.y, base12.y + P2[rel][d], bs));
    long off = ((long)b * NN + i) * HD + d;
    if (APPLY_BN) {
      xbo[off] = f2b(fmaxf(fmaf(val, sc, sh), 0.f));
    } else {
      xo[off] = val;
    }
  }
}

extern "C" void kernel_launch(void* const* d_in, const int* in_sizes, int n_in,
                              void* d_out, int out_size, void* d_ws,
                              size_t ws_size, hipStream_t stream) {
  const float* locs = (const float*)d_in[0];
  const float* le_W0 = (const float*)d_in[1];
  const float* le_b0 = (const float*)d_in[2];
  const float* le_W1 = (const float*)d_in[3];
  const float* le_b1 = (const float*)d_in[4];
  const float* le_bn_g = (const float*)d_in[5];
  const float* le_bn_b = (const float*)d_in[6];
  const float* le_bn_m = (const float*)d_in[7];
  const float* le_bn_v = (const float*)d_in[8];
  const float* le_Wo = (const float*)d_in[9];
  const float* le_bo = (const float*)d_in[10];
  const float* gat_W = (const float*)d_in[11];
  const float* gat_asrc = (const float*)d_in[12];
  const float* gat_adst = (const float*)d_in[13];
  const float* gat_b = (const float*)d_in[14];
  const float* bn_g = (const float*)d_in[15];
  const float* bn_b = (const float*)d_in[16];
  const float* bn_m = (const float*)d_in[17];
  const float* bn_v = (const float*)d_in[18];

  float* out = (float*)d_out;                          // final f32 output
  unsigned short* hb = (unsigned short*)d_ws;          // 8,192,000 bf16
  unsigned short* xb = hb + 8192000;                   // 8,192,000 bf16
  unsigned short* WT = xb + 8192000;                   // 49,152 bf16
  unsigned short* W1T = WT + 49152;                    // 4,096 bf16
  unsigned short* WoWgT = W1T + 4096;                  // 8,192 bf16
  float* biash = (float*)(WoWgT + 8192 + 32);          // 128 f32
  float2* C12 = (float2*)(biash + 128 + 32);           // 1,032,192 float2
  float* es = (float*)(C12 + 1032192);
  float* ed = es + 64000;
  float2* e12 = (float2*)(ed + 64000);                 // 64,000 float2
  float2* ab = e12 + 64000;                            // 64,000 float2
  int* perm = (int*)(ab + 64000);                      // 64,000 int
  int* tlist = perm + 64000;                           // 64,000 int
  int* boffs = tlist + 64000;                          // 64*(NC+2) int
  // total ≈ 43 MB << ws

  k_wprep<<<241, 256, 0, stream>>>(gat_W, le_W1, le_Wo, le_bo, WT, W1T, WoWgT,
                                   biash);
  for (int l = 0; l < 3; ++l) {
    if (l == 0) {
      k_embed_gemm<<<1000, 256, 0, stream>>>(
          locs, le_W0, le_b0, le_b1, le_bn_g, le_bn_b, le_bn_m, le_bn_v, W1T,
          WoWgT, biash, gat_asrc, gat_adst, hb, es, ed);
    } else {
      k_gemm_e<<<1000, 256, 0, stream>>>(xb, WT + l * 16384,
                                         gat_asrc + l * 128,
                                         gat_adst + l * 128, hb, es, ed);
    }
    k_scpfx<<<dim3(NB, 4), 512, 0, stream>>>(es, ed, hb, e12, perm, ab, tlist,
                                             boffs, C12);
    if (l < 2) {
      k_out<true><<<dim3(NB, NC + 1), 128, 0, stream>>>(
          hb, C12, e12, perm, tlist, boffs, ab, gat_b + l * 128,
          bn_g + l * 128, bn_b + l * 128, bn_m + l * 128, bn_v + l * 128,
          nullptr, xb);
    } else {
      k_out<false><<<dim3(NB, NC + 1), 128, 0, stream>>>(
          hb, C12, e12, perm, tlist, boffs, ab, gat_b + 2 * 128, nullptr,
          nullptr, nullptr, nullptr, out, nullptr);
    }
  }
}

// Round 21
// 184.047 us; speedup vs baseline: 2.5223x; 2.5223x over previous
//
#include <hip/hip_runtime.h>
#include <hip/hip_bf16.h>

#define BN_EPS 1e-5f
#define NB 64
#define NN 1000
#define NP 1024
#define HD 128
#define CS 8
#define NC 125  // NN/CS exactly
#define ZS 72   // z1b/z2b LDS row stride (shorts): 144B = 9x16B, odd -> conflict-free

typedef short bf16x8 __attribute__((ext_vector_type(8)));
typedef float f32x4 __attribute__((ext_vector_type(4)));

__device__ __forceinline__ unsigned short f2b(float f) {
  __hip_bfloat16 h = __float2bfloat16(f);
  return *reinterpret_cast<unsigned short*>(&h);
}
__device__ __forceinline__ float b2f(unsigned short u) {
  unsigned v = ((unsigned)u) << 16;
  return __uint_as_float(v);
}
// monotonic float -> uint (unsigned compare == float compare)
__device__ __forceinline__ unsigned tkey(float f) {
  unsigned u = __float_as_uint(f);
  return u ^ ((unsigned)((int)u >> 31) | 0x80000000u);
}
__device__ __forceinline__ float tdec(unsigned m) {
  unsigned u = (m & 0x80000000u) ? (m ^ 0x80000000u) : ~m;
  return __uint_as_float(u);
}

// ---------------------------------------------------------------------------
// Prep: WT[l][n][k]=bf16(Wg[l][k][n]) (49152); W1T[n][k]=bf16(W1[k][n]) (4096);
// WoWgT[c][i]=bf16(sum_d Wo[i][d]*Wg0[d][c]) (8192); biash[c]=bo@Wg0 (128 f32).
// ---------------------------------------------------------------------------
__global__ __launch_bounds__(256) void k_wprep(
    const float* __restrict__ Wg, const float* __restrict__ W1,
    const float* __restrict__ Wo, const float* __restrict__ bo,
    unsigned short* __restrict__ WT, unsigned short* __restrict__ W1T,
    unsigned short* __restrict__ WoWgT, float* __restrict__ biash) {
  int idx = blockIdx.x * 256 + threadIdx.x;
  if (idx < 49152) {
    int lay = idx >> 14, rem = idx & 16383;
    int n = rem >> 7, k = rem & 127;
    WT[idx] = f2b(Wg[lay * 16384 + k * 128 + n]);
  } else if (idx < 53248) {
    int j = idx - 49152;
    int n = j >> 6, k = j & 63;
    W1T[j] = f2b(W1[k * 64 + n]);
  } else if (idx < 61440) {
    int j = idx - 53248;
    int c = j >> 6, i = j & 63;
    float acc = 0.f;
#pragma unroll 4
    for (int d = 0; d < 128; ++d)
      acc = fmaf(Wo[i * 128 + d], Wg[d * 128 + c], acc);
    WoWgT[j] = f2b(acc);  // WoWgT[c*64+i]
  } else if (idx < 61568) {
    int c = idx - 61440;
    float acc = 0.f;
#pragma unroll 4
    for (int d = 0; d < 128; ++d) acc = fmaf(bo[d], Wg[d * 128 + c], acc);
    biash[c] = acc;
  }
}

// ---------------------------------------------------------------------------
// FUSED embed MLP + layer-0 GEMM, MFMA throughout.
//  A: z1 = relu(locs@W0+b0) -> z1b (bf16 LDS [64][ZS])
//  B: z2 = relu(bn(z1@W1+b1)) via MFMA (A=z1b, B=W1T) -> z2b (bf16 LDS)
//  C: h  = z2@(Wo@Wg0) + biash via MFMA (A=z2b, B=WoWgT) -> hb + es/ed
// ---------------------------------------------------------------------------
__global__ __launch_bounds__(256) void k_embed_gemm(
    const float* __restrict__ locs,
    const float* __restrict__ W0, const float* __restrict__ b0,
    const float* __restrict__ b1, const float* __restrict__ g1,
    const float* __restrict__ be1, const float* __restrict__ m1,
    const float* __restrict__ v1, const unsigned short* __restrict__ W1T,
    const unsigned short* __restrict__ WoWgT, const float* __restrict__ biash,
    const float* __restrict__ asrc, const float* __restrict__ adst,
    unsigned short* __restrict__ hb, float* __restrict__ es,
    float* __restrict__ ed) {
  __shared__ __align__(16) unsigned short z1b[64 * ZS];
  __shared__ __align__(16) unsigned short z2b[64 * ZS];
  int tid = threadIdx.x;
  long base = (long)blockIdx.x * 64;

  // ---- A ----
  {
    int d = tid & 63;
    int q = tid >> 6;
    float w0x = W0[d], w0y = W0[64 + d], bb = b0[d];
#pragma unroll
    for (int g = 0; g < 4; ++g) {
#pragma unroll
      for (int i = 0; i < 4; ++i) {
        int n = g * 16 + q * 4 + i;
        float lx = locs[(base + n) * 2 + 0];
        float ly = locs[(base + n) * 2 + 1];
        z1b[n * ZS + d] = f2b(fmaxf(fmaf(lx, w0x, fmaf(ly, w0y, bb)), 0.f));
      }
    }
  }
  __syncthreads();

  int w = tid >> 6, l = tid & 63;
  int r = l & 15, g = l >> 4;

  // ---- B: z2 = relu(bn(z1 @ W1 + b1)), MFMA ----
  {
    f32x4 acc[4];
#pragma unroll
    for (int n = 0; n < 4; ++n) acc[n] = {0.f, 0.f, 0.f, 0.f};
#pragma unroll
    for (int ks = 0; ks < 2; ++ks) {
      bf16x8 a = *(const bf16x8*)&z1b[(w * 16 + r) * ZS + ks * 32 + g * 8];
#pragma unroll
      for (int n = 0; n < 4; ++n) {
        bf16x8 bfr = *(const bf16x8*)&W1T[(n * 16 + r) * 64 + ks * 32 + g * 8];
        acc[n] = __builtin_amdgcn_mfma_f32_16x16x32_bf16(a, bfr, acc[n], 0, 0, 0);
      }
    }
#pragma unroll
    for (int n = 0; n < 4; ++n) {
      int col = n * 16 + r;
      float sc = g1[col] * rsqrtf(v1[col] + BN_EPS);
      float sh = be1[col] - m1[col] * sc;
      float bb = b1[col];
#pragma unroll
      for (int rr = 0; rr < 4; ++rr) {
        float v = fmaxf(fmaf(acc[n][rr] + bb, sc, sh), 0.f);
        z2b[(w * 16 + g * 4 + rr) * ZS + col] = f2b(v);
      }
    }
  }
  __syncthreads();

  // ---- C: h = z2 @ WoWg + biash, MFMA; fused e dots ----
  {
    long rowbase = base + w * 16;
    f32x4 acc[8];
#pragma unroll
    for (int n = 0; n < 8; ++n) acc[n] = {0.f, 0.f, 0.f, 0.f};
#pragma unroll
    for (int ks = 0; ks < 2; ++ks) {
      bf16x8 a = *(const bf16x8*)&z2b[(w * 16 + r) * ZS + ks * 32 + g * 8];
#pragma unroll
      for (int n = 0; n < 8; ++n) {
        bf16x8 bfr = *(const bf16x8*)&WoWgT[(n * 16 + r) * 64 + ks * 32 + g * 8];
        acc[n] = __builtin_amdgcn_mfma_f32_16x16x32_bf16(a, bfr, acc[n], 0, 0, 0);
      }
    }
    float ps[4] = {0.f, 0.f, 0.f, 0.f};
    float pd[4] = {0.f, 0.f, 0.f, 0.f};
#pragma unroll
    for (int n = 0; n < 8; ++n) {
      int col = n * 16 + r;
      float bh = biash[col];
      float sa = asrc[col];
      float sd = adst[col];
#pragma unroll
      for (int rr = 0; rr < 4; ++rr) {
        float v = acc[n][rr] + bh;
        hb[(rowbase + g * 4 + rr) * 128 + col] = f2b(v);
        ps[rr] = fmaf(v, sa, ps[rr]);
        pd[rr] = fmaf(v, sd, pd[rr]);
      }
    }
#pragma unroll
    for (int rr = 0; rr < 4; ++rr) {
#pragma unroll
      for (int m = 1; m <= 8; m <<= 1) {
        ps[rr] += __shfl_xor(ps[rr], m, 64);
        pd[rr] += __shfl_xor(pd[rr], m, 64);
      }
    }
    if (r == 0) {
#pragma unroll
      for (int rr = 0; rr < 4; ++rr) {
        es[rowbase + g * 4 + rr] = ps[rr];
        ed[rowbase + g * 4 + rr] = pd[rr];
      }
    }
  }
}

// ---------------------------------------------------------------------------
// h = xb @ W via MFMA 16x16x32 bf16 (layers 1,2). No LDS.
// ---------------------------------------------------------------------------
__global__ __launch_bounds__(256) void k_gemm_e(
    const unsigned short* __restrict__ xb, const unsigned short* __restrict__ WT,
    const float* __restrict__ asrc, const float* __restrict__ adst,
    unsigned short* __restrict__ hb, float* __restrict__ es,
    float* __restrict__ ed) {
  int tid = threadIdx.x;
  int w = tid >> 6, l = tid & 63;
  long rowbase = (long)blockIdx.x * 64 + w * 16;
  int r = l & 15, g = l >> 4;

  f32x4 acc[8];
#pragma unroll
  for (int n = 0; n < 8; ++n) acc[n] = {0.f, 0.f, 0.f, 0.f};

#pragma unroll
  for (int ks = 0; ks < 4; ++ks) {
    bf16x8 a = *(const bf16x8*)&xb[(rowbase + r) * 128 + ks * 32 + g * 8];
#pragma unroll
    for (int n = 0; n < 8; ++n) {
      bf16x8 bfr = *(const bf16x8*)&WT[(n * 16 + r) * 128 + ks * 32 + g * 8];
      acc[n] = __builtin_amdgcn_mfma_f32_16x16x32_bf16(a, bfr, acc[n], 0, 0, 0);
    }
  }

  float ps[4] = {0.f, 0.f, 0.f, 0.f};
  float pd[4] = {0.f, 0.f, 0.f, 0.f};
#pragma unroll
  for (int n = 0; n < 8; ++n) {
    float sa = asrc[n * 16 + r];
    float sd = adst[n * 16 + r];
#pragma unroll
    for (int rr = 0; rr < 4; ++rr) {
      float v = acc[n][rr];
      hb[(rowbase + g * 4 + rr) * 128 + n * 16 + r] = f2b(v);
      ps[rr] = fmaf(v, sa, ps[rr]);
      pd[rr] = fmaf(v, sd, pd[rr]);
    }
  }
#pragma unroll
  for (int rr = 0; rr < 4; ++rr) {
#pragma unroll
    for (int m = 1; m <= 8; m <<= 1) {
      ps[rr] += __shfl_xor(ps[rr], m, 64);
      pd[rr] += __shfl_xor(pd[rr], m, 64);
    }
  }
  if (r == 0) {
#pragma unroll
    for (int rr = 0; rr < 4; ++rr) {
      es[rowbase + g * 4 + rr] = ps[rr];
      ed[rowbase + g * 4 + rr] = pd[rr];
    }
  }
}

#define CEX(a, b, up)                         \
  do {                                        \
    if (((a) > (b)) == (up)) {                \
      unsigned long long _t = (a);            \
      (a) = (b);                              \
      (b) = _t;                               \
    }                                         \
  } while (0)

// ---------------------------------------------------------------------------
// Fused sort + scan + coeffs + chunk-sums + chunk-prefix + sorted-h emission.
// grid (NB, 4), 512 threads. C12 written interleaved (c1,c2) float2.
// ---------------------------------------------------------------------------
__global__ __launch_bounds__(512) void k_scpfx(
    const float* __restrict__ es, const float* __restrict__ ed,
    const unsigned short* __restrict__ hb, float2* __restrict__ e12,
    int* __restrict__ kcut, float2* __restrict__ ab, float2* __restrict__ C12,
    unsigned short* __restrict__ hs) {
  __shared__ unsigned long long keys[NP];      // 8192 B, live A..D
  __shared__ float smem[(NC + 1) * 64];        // 32256 B overlay: sc | s1,s2
  __shared__ float2 wtot[8];
  float2* sc = (float2*)smem;                  // 1000 float2 (B..C)
  float (*s1)[32] = (float(*)[32])smem;        // 126x32 (D..F)
  float (*s2)[32] = (float(*)[32])(smem + (NC + 1) * 32);
  int tid = threadIdx.x, b = blockIdx.x, dq = blockIdx.y;

  // ---- A: load + u64 bitonic sort ----
  for (int i = tid; i < NP; i += 512) {
    unsigned long long kk;
    if (i < NN) {
      kk = ((unsigned long long)tkey(es[b * NN + i]) << 32) | (unsigned)i;
    } else {
      kk = (0xFF800000ull << 32) | (unsigned)i;  // tkey(+INF) pad
    }
    keys[i] = kk;
  }
  __syncthreads();
  int i0 = tid * 2;
  {
    unsigned long long q0 = keys[i0], q1 = keys[i0 + 1];
    CEX(q0, q1, (i0 & 2) == 0);
    keys[i0] = q0; keys[i0 + 1] = q1;
  }
  __syncthreads();
  for (int k = 4; k <= NP; k <<= 1) {
    for (int j = k >> 1; j >= 2; j >>= 1) {
      int i = ((tid & ~(j - 1)) << 1) | (tid & (j - 1));
      int ixj = i | j;
      bool up = ((i & k) == 0);
      unsigned long long a = keys[i], c = keys[ixj];
      if ((a > c) == up) { keys[i] = c; keys[ixj] = a; }
      __syncthreads();
    }
    {
      unsigned long long q0 = keys[i0], q1 = keys[i0 + 1];
      CEX(q0, q1, (i0 & k) == 0);
      keys[i0] = q0; keys[i0 + 1] = q1;
    }
    __syncthreads();
  }

  // ---- B: decode + hierarchical scan of (e1,e2) -> sc ----
  float2 f0 = make_float2(0.f, 0.f), f1 = make_float2(0.f, 0.f);
  {
    unsigned long long k0 = keys[i0], k1 = keys[i0 + 1];
    if (i0 < NN) {
      float s = tdec((unsigned)(k0 >> 32));
      f0.x = __expf(s);
      f0.y = __expf(0.2f * s);
      if (dq == 0) e12[b * NN + i0] = f0;
    }
    if (i0 + 1 < NN) {
      float s = tdec((unsigned)(k1 >> 32));
      f1.x = __expf(s);
      f1.y = __expf(0.2f * s);
      if (dq == 0) e12[b * NN + i0 + 1] = f1;
    }
  }
  int lane = tid & 63, wid = tid >> 6;
  float tx = f0.x + f1.x, ty = f0.y + f1.y;
  float ix = tx, iy = ty;
#pragma unroll
  for (int dlt = 1; dlt < 64; dlt <<= 1) {
    float ox = __shfl_up(ix, dlt, 64);
    float oy = __shfl_up(iy, dlt, 64);
    if (lane >= dlt) { ix += ox; iy += oy; }
  }
  if (lane == 63) wtot[wid] = make_float2(ix, iy);
  __syncthreads();
  float bx = 0.f, by = 0.f;
#pragma unroll
  for (int ww = 0; ww < 8; ++ww) {
    if (ww < wid) {
      float2 t = wtot[ww];
      bx += t.x;
      by += t.y;
    }
  }
  float exx = bx + ix - tx, eyy = by + iy - ty;  // exclusive at i0
  float in0x = exx + f0.x, in0y = eyy + f0.y;
  if (i0 < NN) sc[i0] = make_float2(in0x, in0y);
  if (i0 + 1 < NN) sc[i0 + 1] = make_float2(in0x + f1.x, in0y + f1.y);
  __syncthreads();

  // ---- C: per-target coefficients (dq==0 only) ----
  if (dq == 0) {
    float s1tot = sc[NN - 1].x;
    for (int i = tid; i < NN; i += 512) {
      float di = ed[b * NN + i];
      unsigned tt = tkey(-di);
      int lo = 0, hi = NP;
      while (lo < hi) {
        int mid = (lo + hi) >> 1;
        if ((unsigned)(keys[mid] >> 32) <= tt) lo = mid + 1; else hi = mid;
      }
      int k = lo;  // #{s_j <= t_i} <= NN (pads are +INF)
      float p1 = (k > 0) ? sc[k - 1].x : 0.f;
      float p2 = (k > 0) ? sc[k - 1].y : 0.f;
      float Ed = __expf(di);
      float Ed2 = __expf(0.2f * di);
      float den = fmaf(Ed, s1tot - p1, Ed2 * p2);
      kcut[b * NN + i] = k;
      ab[b * NN + i] = make_float2(Ed / den, Ed2 / den);
    }
  }
  __syncthreads();  // sc dead after this; s1/s2 may overwrite

  // ---- D: chunk gather via LDS keys; write hs + chunk sums ----
  int d = tid & 31;
  int cl = tid >> 5;  // chunk lane 0..15
  int dglob = dq * 32 + d;
  for (int c = cl; c < NC; c += 16) {
    float v1 = 0.f, v2 = 0.f;
#pragma unroll
    for (int u = 0; u < CS; ++u) {
      int j = c * CS + u;
      unsigned long long kk = keys[j];
      int p = (int)(unsigned)kk;
      float s = tdec((unsigned)(kk >> 32));
      float e1 = __expf(s), e2 = __expf(0.2f * s);
      unsigned short hraw = hb[((long)b * NN + p) * HD + dglob];
      hs[((long)b * NN + j) * HD + dglob] = hraw;
      float hv = b2f(hraw);
      v1 = fmaf(e1, hv, v1);
      v2 = fmaf(e2, hv, v2);
    }
    s1[c][d] = v1;
    s2[c][d] = v2;
  }
  __syncthreads();

  // ---- E: serial exclusive chunk prefix (+ totals) ----
  if (tid < 32) {
    float r = 0.f;
    for (int c = 0; c < NC; ++c) {
      float v = s1[c][tid];
      s1[c][tid] = r;
      r += v;
    }
    s1[NC][tid] = r;
  } else if (tid < 64) {
    int dd = tid - 32;
    float r = 0.f;
    for (int c = 0; c < NC; ++c) {
      float v = s2[c][dd];
      s2[c][dd] = r;
      r += v;
    }
    s2[NC][dd] = r;
  }
  __syncthreads();

  // ---- F: coalesced interleaved C12 store ----
  long basec = (long)b * (NC + 1) * HD + dq * 32;
  for (int i = tid; i < (NC + 1) * 32; i += 512) {
    int c = i >> 5, dd = i & 31;
    C12[basec + (long)c * HD + dd] = make_float2(s1[c][dd], s2[c][dd]);
  }
}

// ---------------------------------------------------------------------------
// out[i] = a_i*(T1 - C1[c_i] - res1) + b_i*(C2[c_i] + res2) + bias.
// C12 interleaved; residual reads hs (sorted-order, streaming). Balanced
// grid (NB, NC): 8 targets/block regardless of data distribution.
// ---------------------------------------------------------------------------
template <bool APPLY_BN>
__global__ __launch_bounds__(128) void k_out(
    const unsigned short* __restrict__ hs, const float2* __restrict__ C12,
    const float2* __restrict__ e12, const int* __restrict__ kcut,
    const float2* __restrict__ ab, const float* __restrict__ bias,
    const float* __restrict__ bng, const float* __restrict__ bnb,
    const float* __restrict__ bnm, const float* __restrict__ bnv,
    float* __restrict__ xo, unsigned short* __restrict__ xbo) {
  int d = threadIdx.x, b = blockIdx.x;
  int i0 = blockIdx.y * 8;
  float T1 = C12[((long)b * (NC + 1) + NC) * HD + d].x;
  float bs = bias[d];
  float sc = 0.f, sh = 0.f;
  if (APPLY_BN) {
    float g = bng[d], bb = bnb[d], m = bnm[d], v = bnv[d];
    sc = g * rsqrtf(v + BN_EPS);
    sh = bb - m * sc;
  }
  for (int i = i0; i < i0 + 8; ++i) {
    int k = kcut[b * NN + i];
    float2 coeff = ab[b * NN + i];
    int c = k >> 3;
    float2 base12 = C12[((long)b * (NC + 1) + c) * HD + d];
    float p1 = 0.f, p2 = 0.f;
    for (int j = c * CS; j < k; ++j) {
      float hv = b2f(hs[((long)b * NN + j) * HD + d]);
      float2 e = e12[b * NN + j];
      p1 = fmaf(e.x, hv, p1);
      p2 = fmaf(e.y, hv, p2);
    }
    float val = fmaf(coeff.x, T1 - base12.x - p1,
                     fmaf(coeff.y, base12.y + p2, bs));
    long off = ((long)b * NN + i) * HD + d;
    if (APPLY_BN) {
      xbo[off] = f2b(fmaxf(fmaf(val, sc, sh), 0.f));
    } else {
      xo[off] = val;
    }
  }
}

extern "C" void kernel_launch(void* const* d_in, const int* in_sizes, int n_in,
                              void* d_out, int out_size, void* d_ws,
                              size_t ws_size, hipStream_t stream) {
  const float* locs = (const float*)d_in[0];
  const float* le_W0 = (const float*)d_in[1];
  const float* le_b0 = (const float*)d_in[2];
  const float* le_W1 = (const float*)d_in[3];
  const float* le_b1 = (const float*)d_in[4];
  const float* le_bn_g = (const float*)d_in[5];
  const float* le_bn_b = (const float*)d_in[6];
  const float* le_bn_m = (const float*)d_in[7];
  const float* le_bn_v = (const float*)d_in[8];
  const float* le_Wo = (const float*)d_in[9];
  const float* le_bo = (const float*)d_in[10];
  const float* gat_W = (const float*)d_in[11];
  const float* gat_asrc = (const float*)d_in[12];
  const float* gat_adst = (const float*)d_in[13];
  const float* gat_b = (const float*)d_in[14];
  const float* bn_g = (const float*)d_in[15];
  const float* bn_b = (const float*)d_in[16];
  const float* bn_m = (const float*)d_in[17];
  const float* bn_v = (const float*)d_in[18];

  float* out = (float*)d_out;                          // final f32 output
  unsigned short* hb = (unsigned short*)d_ws;          // 8,192,000 bf16
  unsigned short* hs = hb + 8192000;                   // 8,192,000 bf16
  unsigned short* xb = hs + 8192000;                   // 8,192,000 bf16
  unsigned short* WT = xb + 8192000;                   // 49,152 bf16
  unsigned short* W1T = WT + 49152;                    // 4,096 bf16
  unsigned short* WoWgT = W1T + 4096;                  // 8,192 bf16
  float* biash = (float*)(WoWgT + 8192 + 32);          // 128 f32
  float2* C12 = (float2*)(biash + 128 + 32);           // 1,032,192 float2
  float* es = (float*)(C12 + 1032192);
  float* ed = es + 64000;
  float2* e12 = (float2*)(ed + 64000);                 // 64,000 float2
  float2* ab = e12 + 64000;                            // 64,000 float2
  int* kcut = (int*)(ab + 64000);
  // total ≈ 59 MB << ws

  k_wprep<<<241, 256, 0, stream>>>(gat_W, le_W1, le_Wo, le_bo, WT, W1T, WoWgT,
                                   biash);
  for (int l = 0; l < 3; ++l) {
    if (l == 0) {
      k_embed_gemm<<<1000, 256, 0, stream>>>(
          locs, le_W0, le_b0, le_b1, le_bn_g, le_bn_b, le_bn_m, le_bn_v, W1T,
          WoWgT, biash, gat_asrc, gat_adst, hb, es, ed);
    } else {
      k_gemm_e<<<1000, 256, 0, stream>>>(xb, WT + l * 16384,
                                         gat_asrc + l * 128,
                                         gat_adst + l * 128, hb, es, ed);
    }
    k_scpfx<<<dim3(NB, 4), 512, 0, stream>>>(es, ed, hb, e12, kcut, ab, C12,
                                             hs);
    if (l < 2) {
      k_out<true><<<dim3(NB, NC), 128, 0, stream>>>(
          hs, C12, e12, kcut, ab, gat_b + l * 128, bn_g + l * 128,
          bn_b + l * 128, bn_m + l * 128, bn_v + l * 128, nullptr, xb);
    } else {
      k_out<false><<<dim3(NB, NC), 128, 0, stream>>>(
          hs, C12, e12, kcut, ab, gat_b + 2 * 128, nullptr, nullptr, nullptr,
          nullptr, out, nullptr);
    }
  }
}